// Round 8
// baseline (215.637 us; speedup 1.0000x reference)
//
#include <hip/hip_runtime.h>
#include <hip/hip_bf16.h>

#define BB 128
#define VV 128000
#define NCHH 4                  // hist chunks/row (partial hists, no atomics)
#define CHH (VV / NCHH)         // 32000
#define NCHG 8                  // gather chunks/row
#define CHG (VV / NCHG)         // 16000
#define NBIN 4096               // fx >> 20; crossing-bin worst ~900 -> n <= ~1900 < 2048
#define NCOPY 4                 // LDS hist copies (lane&3)
#define HSTR (NBIN + 8)         // 4104 words: copies at banks 0/8/16/24 (conflict-free)
#define CEXP 16.0f              // fixed softmax scale: l/T in [-20,20] -> exp arg in [-36,4]
static constexpr float BF16_LO = -3.3e38f;   // finite in bf16 (max bf16 = 3.3895e38)
static_assert(VV < (1 << 17), "idx must fit 17 bits");
static_assert((CHH % 8) == 0 && (CHG % 4) == 0, "vector passes");

__device__ __forceinline__ unsigned int flip_f(unsigned int b) {
    return b ^ ((b & 0x80000000u) ? 0xFFFFFFFFu : 0x80000000u);
}
// key layout: [60:49] = 4095-bin (order-consistent tag), [48:17] = ~p_bits, [16:0] = idx
__device__ __forceinline__ float key_p(unsigned long long k) {
    return __uint_as_float(~(unsigned int)(k >> 17));   // truncation keeps bits 17..48
}
__device__ __forceinline__ int key_i(unsigned long long k) {
    return (int)(k & 0x1FFFFull);
}
__device__ __forceinline__ int key_b(unsigned long long k) {
    return 4095 - (int)(k >> 49);
}

// ---------------- K1: partial histograms (4 lane-parity LDS copies, bank-staggered)
// + Z partials + cntv zero + tail BF16_LO fill of the logprob output ----------------
__global__ __launch_bounds__(1024) void k_hist(
    const float* __restrict__ logits, const float* __restrict__ temps,
    unsigned int* __restrict__ ghist, float* __restrict__ zpart,
    int* __restrict__ cntv, __hip_bfloat16* __restrict__ d_out)
{
    const int row = blockIdx.y, chunk = blockIdx.x;
    const int tid = threadIdx.x;
    const int w = tid >> 6, lane = tid & 63;
    const float rT = 1.0f / temps[row];

    __shared__ unsigned int hist[NCOPY * HSTR];
    __shared__ float red[16];

    for (int j = tid; j < NCOPY * HSTR; j += 1024) hist[j] = 0;
    unsigned int* myh = hist + (lane & 3) * HSTR;   // 4-way copy split by lane parity
    if (chunk == 0 && tid == 0) cntv[row] = 0;      // k_gather's atomic base (pre-gather)
    __syncthreads();

    // main loop: 1-ahead register prefetch (2 blocks/CU + ILP hide HBM latency)
    const float4* lp4 = (const float4*)(logits + (size_t)row * VV + (size_t)chunk * CHH);
    const int N4 = CHH / 4;
    float zs = 0.f;
    int i = tid;
    bool have = i < N4;
    float4 cur = have ? lp4[i] : make_float4(0.f, 0.f, 0.f, 0.f);
    while (have) {
        const int inext = i + 1024;
        const bool hnext = inext < N4;
        float4 nxt = hnext ? lp4[inext] : make_float4(0.f, 0.f, 0.f, 0.f);
        float e4[4] = {cur.x, cur.y, cur.z, cur.w};
        #pragma unroll
        for (int e = 0; e < 4; ++e) {
            atomicAdd(&myh[flip_f(__float_as_uint(e4[e])) >> 20], 1u);  // LDS atomic
            zs += __expf(fmaf(e4[e], rT, -CEXP));
        }
        cur = nxt; i = inext; have = hnext;
    }
    #pragma unroll
    for (int off = 32; off > 0; off >>= 1) zs += __shfl_down(zs, off);
    if (lane == 0) red[w] = zs;
    __syncthreads();

    // merge 4 copies, publish disjoint partial (plain coalesced stores)
    unsigned int* gh = ghist + ((size_t)row * NCHH + chunk) * NBIN;
    for (int j = tid; j < NBIN; j += 1024)
        gh[j] = hist[j] + hist[HSTR + j] + hist[2 * HSTR + j] + hist[3 * HSTR + j];
    if (tid == 0) {
        float z = 0.f;
        #pragma unroll
        for (int i2 = 0; i2 < 16; ++i2) z += red[i2];
        zpart[row * NCHH + chunk] = z;
    }

    // tail fill of this block's logprob slice: no barrier after -> drains at retire
    {
        __hip_bfloat16 hlo = __float2bfloat16(BF16_LO);
        unsigned int pat = ((unsigned int)*(unsigned short*)&hlo) * 0x10001u;
        uint4 fv = make_uint4(pat, pat, pat, pat);
        uint4* dst = (uint4*)(d_out + BB + (size_t)row * VV + (size_t)chunk * CHH);
        for (int j = tid; j < CHH / 8; j += 1024) dst[j] = fv;   // 8 bf16 / store
    }
}

// ---------------- K2: gather candidates; each block recomputes the row threshold
// from ghist (L2-hot, deterministic -> identical t across the row's 8 blocks) ----------------
__global__ __launch_bounds__(256) void k_gather(
    const float* __restrict__ logits, const float* __restrict__ temps,
    const unsigned int* __restrict__ ghist, const float* __restrict__ zpart,
    int* __restrict__ cntv, unsigned long long* __restrict__ cand)
{
    const int row = blockIdx.y, chunk = blockIdx.x;
    const int tid = threadIdx.x;
    const int w = tid >> 6, lane = tid & 63;

    __shared__ unsigned long long lbuf[2048];
    __shared__ int s_n, s_base;
    __shared__ unsigned int s_t;
    __shared__ unsigned int wsum[4];
    __shared__ int wcnt[4];
    if (tid == 0) s_n = 0;

    // ---- inline threshold: 16 bins/thread over 4096 bins, 4 partials summed ----
    unsigned int bins[16];
    #pragma unroll
    for (int b = 0; b < 16; ++b) bins[b] = 0;
    #pragma unroll
    for (int c = 0; c < NCHH; ++c) {
        const unsigned int* h = ghist + ((size_t)row * NCHH + c) * NBIN + tid * 16;
        uint4 a0 = *(const uint4*)h,       a1 = *(const uint4*)(h + 4);
        uint4 a2 = *(const uint4*)(h + 8), a3 = *(const uint4*)(h + 12);
        bins[0] += a0.x; bins[1] += a0.y; bins[2]  += a0.z; bins[3]  += a0.w;
        bins[4] += a1.x; bins[5] += a1.y; bins[6]  += a1.z; bins[7]  += a1.w;
        bins[8] += a2.x; bins[9] += a2.y; bins[10] += a2.z; bins[11] += a2.w;
        bins[12] += a3.x; bins[13] += a3.y; bins[14] += a3.z; bins[15] += a3.w;
    }
    unsigned int s16 = 0;
    #pragma unroll
    for (int b = 0; b < 16; ++b) s16 += bins[b];

    unsigned int v = s16;                 // wave-inclusive suffix sum over lanes
    #pragma unroll
    for (int off = 1; off < 64; off <<= 1) {
        unsigned int o = __shfl_down(v, off);
        v += (lane + off < 64) ? o : 0u;
    }
    if (lane == 0) wsum[w] = v;
    __syncthreads();
    unsigned int above = 0;
    #pragma unroll
    for (int ww = 0; ww < 4; ++ww) if (ww > w) above += wsum[ww];
    const unsigned int S = v + above;     // count of elements in bins >= tid*16
    {
        unsigned long long bge = __ballot(S >= 1024u);
        if (lane == 0) wcnt[w] = __popcll(bge);
    }
    __syncthreads();
    {
        int tc = wcnt[0] + wcnt[1] + wcnt[2] + wcnt[3] - 1;   // crossing thread
        if (tid == tc) {
            unsigned int acc = S - s16;
            int bsel = -1;
            #pragma unroll
            for (int b = 15; b >= 0; --b) {  // register-only fine scan, no break
                acc += bins[b];
                if (bsel < 0 && acc >= 1024u) bsel = tid * 16 + b;
            }
            s_t = ((unsigned int)bsel) << 20;
        }
    }
    __syncthreads();

    // ---- gather ----
    const float rT = 1.0f / temps[row];
    const float Z = zpart[row * NCHH + 0] + zpart[row * NCHH + 1]
                  + zpart[row * NCHH + 2] + zpart[row * NCHH + 3];
    const float invZ = 1.0f / Z;
    const unsigned int t = s_t;
    const int base = chunk * CHG;
    const float4* lp4 = (const float4*)(logits + (size_t)row * VV + base);

    for (int i = tid; i < CHG / 4; i += 256) {
        float4 vv = lp4[i];
        float e4[4] = {vv.x, vv.y, vv.z, vv.w};
        #pragma unroll
        for (int e = 0; e < 4; ++e) {
            unsigned int fx = flip_f(__float_as_uint(e4[e]));
            if (fx >= t) {
                float p = __expf(fmaf(e4[e], rT, -CEXP)) * invZ;
                unsigned long long binv = 4095ull - (unsigned long long)(fx >> 20);
                int pos = atomicAdd(&s_n, 1);           // LDS atomic: cheap
                if (pos < 2048)
                    lbuf[pos] = (binv << 49)
                              | ((unsigned long long)(~__float_as_uint(p)) << 17)
                              | (unsigned long long)(base + i * 4 + e);
            }
        }
    }
    __syncthreads();
    const int n = (s_n < 2048) ? s_n : 2048;
    if (tid == 0) s_base = atomicAdd(&cntv[row], n);    // one global atomic/block
    __syncthreads();
    const int gbase = s_base;
    for (int i = tid; i < n; i += 256) {
        int dst = gbase + i;
        if (dst < 2048) cand[(size_t)row * 2048 + dst] = lbuf[i];
    }
}

// ---------------- K3: counting-sort placement via hist suffix-sums + within-bin
// ranking (only bins reaching rank<1024) + cumsum + cuts + scatter ----------------
__global__ __launch_bounds__(1024) void k_sample(
    const unsigned long long* __restrict__ cand, const int* __restrict__ cntv,
    const unsigned int* __restrict__ ghist,
    const int* __restrict__ top_ks, const float* __restrict__ top_ps,
    const float* __restrict__ min_ps, const float* __restrict__ u_arr,
    __hip_bfloat16* __restrict__ d_out)
{
    const int row = blockIdx.x;
    const int tid = threadIdx.x;
    const int w = tid >> 6, lane = tid & 63;
    const float top_p = top_ps[row];

    __shared__ __align__(16) unsigned int sfx[NBIN + 4]; // sfx[b] = count in bins >= b
    __shared__ __align__(16) unsigned int cnt[NBIN];     // arrival counters
    __shared__ __align__(16) unsigned long long skey[2048];  // bin-grouped candidates
    __shared__ __align__(16) unsigned long long srt[1024];   // exact ranks 0..1023
    __shared__ __align__(16) float pv[1024];
    __shared__ __align__(16) float cdf[1024];
    __shared__ unsigned int wsum[16];
    __shared__ int sA[16], sB[16], sC[16];
    __shared__ double sD[16];
    __shared__ int s_R, s_M, s_Kp;
    __shared__ float s_tgt, s_thr, s_pcut, s_logzp;

    // ---- phase A: suffix-sum of merged histogram into LDS (4 bins/thread) ----
    unsigned int bins[4] = {0, 0, 0, 0};
    #pragma unroll
    for (int c = 0; c < NCHH; ++c) {
        const unsigned int* h = ghist + ((size_t)row * NCHH + c) * NBIN + tid * 4;
        uint4 a = *(const uint4*)h;
        bins[0] += a.x; bins[1] += a.y; bins[2] += a.z; bins[3] += a.w;
    }
    unsigned int lsfx[4];                // local suffix within my 4 bins
    lsfx[3] = bins[3];
    lsfx[2] = bins[2] + lsfx[3];
    lsfx[1] = bins[1] + lsfx[2];
    lsfx[0] = bins[0] + lsfx[1];
    const unsigned int s4 = lsfx[0];

    unsigned int v = s4;
    #pragma unroll
    for (int off = 1; off < 64; off <<= 1) {
        unsigned int o = __shfl_down(v, off);
        v += (lane + off < 64) ? o : 0u;
    }
    if (lane == 0) wsum[w] = v;
    __syncthreads();
    unsigned int above = 0;
    for (int ww = w + 1; ww < 16; ++ww) above += wsum[ww];
    const unsigned int thr_above = (v + above) - s4;   // count strictly above my bins
    *(uint4*)&sfx[tid * 4] = make_uint4(thr_above + lsfx[0], thr_above + lsfx[1],
                                        thr_above + lsfx[2], thr_above + lsfx[3]);
    *(uint4*)&cnt[tid * 4] = make_uint4(0, 0, 0, 0);
    if (tid == 0) sfx[NBIN] = 0;
    __syncthreads();

    // ---- placement: slot = rank-base of bin + arrival offset (dense [0,n)) ----
    const int n = min(cntv[row], 2048);
    for (int i = tid; i < n; i += 1024) {
        unsigned long long k = cand[(size_t)row * 2048 + i];
        int b = key_b(k);
        unsigned int off = atomicAdd(&cnt[b], 1u);
        unsigned int slot = sfx[b + 1] + off;
        if (slot < 2048u) skey[slot] = k;
    }
    __syncthreads();

    // ---- within-bin exact ranking; skip bins whose whole segment is rank>=1024 ----
    #pragma unroll
    for (int q = 0; q < 2; ++q) {
        const int s = tid + q * 1024;
        if (s < n) {
            unsigned long long k = skey[s];
            int b = key_b(k);
            int lo = (int)sfx[b + 1];
            if (lo < 1024) {
                int hi = (int)sfx[b]; if (hi > n) hi = n;
                int r = lo;
                for (int j = lo; j < hi; ++j) r += (skey[j] < k);
                if (r < 1024) { srt[r] = k; pv[r] = key_p(k); }
            }
        }
    }
    __syncthreads();

    // ---- serial exact f32 cumsum (matches ref order) ----
    if (tid == 0) {
        float s = 0.f;
        for (int j = 0; j < 1024; j += 8) {
            float4 q0 = *(const float4*)&pv[j];
            float4 q1 = *(const float4*)&pv[j + 4];
            s += q0.x; cdf[j + 0] = s;
            s += q0.y; cdf[j + 1] = s;
            s += q0.z; cdf[j + 2] = s;
            s += q0.w; cdf[j + 3] = s;
            s += q1.x; cdf[j + 4] = s;
            s += q1.y; cdf[j + 5] = s;
            s += q1.z; cdf[j + 6] = s;
            s += q1.w; cdf[j + 7] = s;
        }
        s_thr = pv[0] * min_ps[row];
    }
    __syncthreads();

    // ---- crossing rank R and min-p cut M via ballot + wave-0 shfl reduce ----
    {
        float p = pv[tid];
        float a = cdf[tid] - p;                        // == ref csum - probs_sort
        unsigned long long bx = __ballot(a > top_p);   // excluded by top-p
        unsigned long long bm = __ballot(p < s_thr);   // below min-p threshold
        if (lane == 0) {
            sA[w] = bx ? (w * 64 + __builtin_ctzll(bx)) : (1 << 30);
            sB[w] = bm ? (w * 64 + __builtin_ctzll(bm)) : (1 << 30);
        }
    }
    __syncthreads();
    if (w == 0) {
        int a = (lane < 16) ? sA[lane] : (1 << 30);
        int b2 = (lane < 16) ? sB[lane] : (1 << 30);
        #pragma unroll
        for (int off = 8; off > 0; off >>= 1) {
            a = min(a, __shfl_down(a, off));
            b2 = min(b2, __shfl_down(b2, off));
        }
        if (lane == 0) { s_R = a; s_M = b2; }
    }
    __syncthreads();

    const int R = s_R;
    const int Reff = (R <= 1023) ? R : 1024;

    // ---- zp mass: f64 parallel sum of pv[0..Reff) ----
    {
        double zc = (tid < Reff) ? (double)pv[tid] : 0.0;
        for (int off = 32; off > 0; off >>= 1) zc += __shfl_down(zc, off);
        if (lane == 0) sD[w] = zc;
    }
    __syncthreads();
    if (w == 0) {
        double z = (lane < 16) ? sD[lane] : 0.0;
        #pragma unroll
        for (int off = 8; off > 0; off >>= 1) z += __shfl_down(z, off);
        if (lane == 0) {
            float zpv;
            if (R <= 1023)               zpv = (float)z;   // exact kept mass
            else if (cdf[1023] > top_p)  zpv = (float)z;   // rank-1024 crossing
            else                         zpv = top_p;      // beyond 1024: zp in (top_p, top_p+1e-3]
            s_pcut  = pv[Reff - 1];
            s_logzp = logf(zpv);

            int K = top_ks[row]; if (Reff < K) K = Reff; if (K > 1024) K = 1024;
            int Kp = (s_M < K) ? s_M : K;                  // min-p suffix cut (Kp >= 1)
            s_Kp = Kp;
            s_tgt = u_arr[row] * cdf[Kp - 1];              // u * cdf[-1], f32
        }
    }
    __syncthreads();

    // ---- parallel count of (cdf < target) ----
    {
        const int Kp = s_Kp; const float tgt = s_tgt;
        bool lt = (tid < Kp) && (cdf[tid] < tgt);
        unsigned long long bc = __ballot(lt);
        if (lane == 0) sC[w] = __popcll(bc);
    }
    __syncthreads();

    // ---- scatter kept logprobs from the (bin-grouped, unsorted) candidate list ----
    {
        const float pcut = s_pcut, logzp = s_logzp;
        for (int i = tid; i < n; i += 1024) {
            unsigned long long k = skey[i];
            float p = key_p(k);
            if (p >= pcut) {
                float val = __logf(p) - logzp;
                if (!(val >= BF16_LO)) val = BF16_LO;  // kills -inf / NaN
                d_out[BB + (size_t)row * VV + key_i(k)] = __float2bfloat16(val);
            }
        }
    }
    if (w == 0) {
        int c2 = (lane < 16) ? sC[lane] : 0;
        #pragma unroll
        for (int off = 8; off > 0; off >>= 1) c2 += __shfl_down(c2, off);
        if (lane == 0) {
            const unsigned long long ktok = srt[c2];   // c2 <= Kp-1 <= 1023
            const int token = key_i(ktok);
            d_out[row] = __float2bfloat16((float)token);   // token id (bf16 out)
            float tval = __logf(key_p(ktok)) - s_logzp;    // token always kept
            if (!(tval >= BF16_LO)) tval = BF16_LO;
            d_out[(size_t)BB * VV + BB + row] = __float2bfloat16(tval);
        }
    }
}

// ---------------- host ----------------
extern "C" void kernel_launch(void* const* d_in, const int* in_sizes, int n_in,
                              void* d_out, int out_size, void* d_ws, size_t ws_size,
                              hipStream_t stream) {
    const float* logits = (const float*)d_in[0];
    const float* temps  = (const float*)d_in[1];
    const int*   top_ks = (const int*)d_in[2];
    const float* top_ps = (const float*)d_in[3];
    const float* min_ps = (const float*)d_in[4];
    const float* u      = (const float*)d_in[5];
    __hip_bfloat16* out = (__hip_bfloat16*)d_out;

    char* wsb = (char*)d_ws;
    unsigned int* ghist = (unsigned int*)wsb;                       // 8 MiB (4 partials/row)
    float* zpart  = (float*)(wsb + (size_t)BB * NCHH * NBIN * 4);   // 512 f32
    int* cntv     = (int*)(zpart + BB * NCHH);
    unsigned long long* cand =
        (unsigned long long*)(wsb + ((size_t)BB * NCHH * NBIN * 4 + 65536)); // 2 MiB

    k_hist<<<dim3(NCHH, BB), 1024, 0, stream>>>(logits, temps, ghist, zpart, cntv, out);
    k_gather<<<dim3(NCHG, BB), 256, 0, stream>>>(logits, temps, ghist, zpart, cntv, cand);
    k_sample<<<BB, 1024, 0, stream>>>(cand, cntv, ghist, top_ks, top_ps, min_ps, u, out);
}

// Round 9
// 162.679 us; speedup vs baseline: 1.3255x; 1.3255x over previous
//
#include <hip/hip_runtime.h>
#include <hip/hip_bf16.h>

#define BB 128
#define VV 128000
#define NCHH 4                  // hist chunks/row (partial hists, no atomics)
#define CHH (VV / NCHH)         // 32000
#define NCHG 8                  // gather chunks/row
#define CHG (VV / NCHG)         // 16000
#define NBIN 8192               // fx >> 19
#define HPAD 16                 // bank-shift pad between the 2 LDS hist copies
#define CEXP 16.0f              // fixed softmax scale: l/T in [-20,20] -> exp arg in [-36,4]
static constexpr float BF16_LO = -3.3e38f;   // finite in bf16 (max bf16 = 3.3895e38)
static_assert(VV < (1 << 17), "idx must fit 17 bits");
static_assert((CHH % 8) == 0 && (CHG % 8) == 0, "vector passes");

__device__ __forceinline__ unsigned int flip_f(unsigned int b) {
    return b ^ ((b & 0x80000000u) ? 0xFFFFFFFFu : 0x80000000u);
}
// key layout: [63:49] = 8191-bin (order-consistent tag), [48:17] = ~p_bits, [16:0] = idx
__device__ __forceinline__ float key_p(unsigned long long k) {
    return __uint_as_float(~(unsigned int)(k >> 17));   // truncation keeps bits 17..48
}
__device__ __forceinline__ int key_i(unsigned long long k) {
    return (int)(k & 0x1FFFFull);
}
__device__ __forceinline__ int key_b(unsigned long long k) {
    return 8191 - (int)(k >> 49);
}

// ---------------- K1: partial histograms (2 lane-parity LDS copies, bank-shifted)
// + Z partials (fill moved to k_gather) ----------------
__global__ __launch_bounds__(1024) void k_hist(
    const float* __restrict__ logits, const float* __restrict__ temps,
    unsigned int* __restrict__ ghist, float* __restrict__ zpart)
{
    const int row = blockIdx.y, chunk = blockIdx.x;
    const int tid = threadIdx.x;
    const int w = tid >> 6, lane = tid & 63;
    const float rT = 1.0f / temps[row];

    __shared__ unsigned int hist[2 * (NBIN + HPAD)];  // copy by LANE parity
    __shared__ float red[16];

    for (int j = tid; j < 2 * (NBIN + HPAD); j += 1024) hist[j] = 0;
    unsigned int* myh = hist + (lane & 1) * (NBIN + HPAD);
    __syncthreads();

    // main loop: 1-ahead register prefetch (2 blocks/CU + ILP hide HBM latency)
    const float4* lp4 = (const float4*)(logits + (size_t)row * VV + (size_t)chunk * CHH);
    const int N4 = CHH / 4;
    float zs = 0.f;
    int i = tid;
    bool have = i < N4;
    float4 cur = have ? lp4[i] : make_float4(0.f, 0.f, 0.f, 0.f);
    while (have) {
        const int inext = i + 1024;
        const bool hnext = inext < N4;
        float4 nxt = hnext ? lp4[inext] : make_float4(0.f, 0.f, 0.f, 0.f);
        float e4[4] = {cur.x, cur.y, cur.z, cur.w};
        #pragma unroll
        for (int e = 0; e < 4; ++e) {
            atomicAdd(&myh[flip_f(__float_as_uint(e4[e])) >> 19], 1u);  // LDS atomic
            zs += __expf(fmaf(e4[e], rT, -CEXP));
        }
        cur = nxt; i = inext; have = hnext;
    }
    #pragma unroll
    for (int off = 32; off > 0; off >>= 1) zs += __shfl_down(zs, off);
    if (lane == 0) red[w] = zs;
    __syncthreads();

    // merge copies, publish disjoint partial (plain coalesced stores)
    unsigned int* gh = ghist + ((size_t)row * NCHH + chunk) * NBIN;
    for (int j = tid; j < NBIN; j += 1024) gh[j] = hist[j] + hist[NBIN + HPAD + j];
    if (tid == 0) {
        float z = 0.f;
        #pragma unroll
        for (int i2 = 0; i2 < 16; ++i2) z += red[i2];
        zpart[row * NCHH + chunk] = z;
    }
}

// ---------------- K2: fully-parallel rank-1024 threshold + Z finalize ----------------
__global__ __launch_bounds__(1024) void k_thresh(
    const unsigned int* __restrict__ ghist, const float* __restrict__ zpart,
    float* __restrict__ Zv, unsigned int* __restrict__ tv, int* __restrict__ cntv)
{
    const int row = blockIdx.x;
    const int tid = threadIdx.x;
    const int w = tid >> 6, lane = tid & 63;
    __shared__ unsigned int wsum[16];
    __shared__ int wcnt[16];

    unsigned int bins[8] = {0, 0, 0, 0, 0, 0, 0, 0};
    #pragma unroll
    for (int c = 0; c < NCHH; ++c) {
        const unsigned int* h = ghist + ((size_t)row * NCHH + c) * NBIN + tid * 8;
        uint4 a0 = *(const uint4*)h, a1 = *(const uint4*)(h + 4);
        bins[0] += a0.x; bins[1] += a0.y; bins[2] += a0.z; bins[3] += a0.w;
        bins[4] += a1.x; bins[5] += a1.y; bins[6] += a1.z; bins[7] += a1.w;
    }
    unsigned int s8 = 0;
    #pragma unroll
    for (int b = 0; b < 8; ++b) s8 += bins[b];

    // wave-inclusive suffix sum over lanes, then cross-wave totals
    unsigned int v = s8;
    #pragma unroll
    for (int off = 1; off < 64; off <<= 1) {
        unsigned int o = __shfl_down(v, off);
        v += (lane + off < 64) ? o : 0u;
    }
    if (lane == 0) wsum[w] = v;
    __syncthreads();
    unsigned int above = 0;
    for (int ww = w + 1; ww < 16; ++ww) above += wsum[ww];
    const unsigned int S = v + above;    // count of elements in bins >= tid*8

    {
        unsigned long long bge = __ballot(S >= 1024u);
        if (lane == 0) wcnt[w] = __popcll(bge);
    }
    __syncthreads();
    {
        int tc = -1;
        for (int ww = 0; ww < 16; ++ww) tc += wcnt[ww];   // crossing thread
        if (tid == tc) {
            unsigned int acc = S - s8;       // count strictly above my 8 bins
            int bsel = -1;
            #pragma unroll
            for (int b = 7; b >= 0; --b) {   // register-only, no break
                acc += bins[b];
                if (bsel < 0 && acc >= 1024u) bsel = tid * 8 + b;
            }
            tv[row] = ((unsigned int)bsel) << 19;
        }
    }
    if (tid == 0) {
        float Z = 0.f;
        #pragma unroll
        for (int c = 0; c < NCHH; ++c) Z += zpart[row * NCHH + c];
        Zv[row] = Z;
        cntv[row] = 0;
    }
}

// ---------------- K3: gather candidates (bin tag in key) + BF16_LO background fill
// of this block's logprob slice (1024 blocks have BW/latency headroom) ----------------
__global__ __launch_bounds__(256) void k_gather(
    const float* __restrict__ logits, const float* __restrict__ temps,
    const float* __restrict__ Zv, const unsigned int* __restrict__ tv,
    int* __restrict__ cntv, unsigned long long* __restrict__ cand,
    __hip_bfloat16* __restrict__ d_out)
{
    const int row = blockIdx.y, chunk = blockIdx.x;
    const int tid = threadIdx.x;
    const float rT = 1.0f / temps[row], invZ = 1.0f / Zv[row];
    const unsigned int t = tv[row];
    const int base = chunk * CHG;
    const float4* lp4 = (const float4*)(logits + (size_t)row * VV + base);

    __shared__ unsigned long long lbuf[2048];
    __shared__ int s_n, s_base;
    if (tid == 0) s_n = 0;

    // fire-and-forget fill of this block's logprob slice (stream-ordered before k_sample)
    {
        __hip_bfloat16 hlo = __float2bfloat16(BF16_LO);
        unsigned int pat = ((unsigned int)*(unsigned short*)&hlo) * 0x10001u;
        uint4 fv = make_uint4(pat, pat, pat, pat);
        uint4* dst = (uint4*)(d_out + BB + (size_t)row * VV + base);
        for (int j = tid; j < CHG / 8; j += 256) dst[j] = fv;   // 8 bf16 / store
    }
    __syncthreads();

    for (int i = tid; i < CHG / 4; i += 256) {
        float4 vv = lp4[i];
        float e4[4] = {vv.x, vv.y, vv.z, vv.w};
        #pragma unroll
        for (int e = 0; e < 4; ++e) {
            unsigned int fx = flip_f(__float_as_uint(e4[e]));
            if (fx >= t) {
                float p = __expf(fmaf(e4[e], rT, -CEXP)) * invZ;
                unsigned long long binv = 8191ull - (unsigned long long)(fx >> 19);
                int pos = atomicAdd(&s_n, 1);           // LDS atomic: cheap
                if (pos < 2048)
                    lbuf[pos] = (binv << 49)
                              | ((unsigned long long)(~__float_as_uint(p)) << 17)
                              | (unsigned long long)(base + i * 4 + e);
            }
        }
    }
    __syncthreads();
    const int n = (s_n < 2048) ? s_n : 2048;
    if (tid == 0) s_base = atomicAdd(&cntv[row], n);    // one global atomic/block
    __syncthreads();
    const int gbase = s_base;
    for (int i = tid; i < n; i += 256) {
        int dst = gbase + i;
        if (dst < 2048) cand[(size_t)row * 2048 + dst] = lbuf[i];
    }
}

// ---------------- K4: counting-sort placement via hist suffix-sums + within-bin
// ranking (skip rank>=1024 segments; singleton fast path) + cumsum + cuts + scatter ----------------
__global__ __launch_bounds__(1024) void k_sample(
    const unsigned long long* __restrict__ cand, const int* __restrict__ cntv,
    const unsigned int* __restrict__ ghist,
    const int* __restrict__ top_ks, const float* __restrict__ top_ps,
    const float* __restrict__ min_ps, const float* __restrict__ u_arr,
    __hip_bfloat16* __restrict__ d_out)
{
    const int row = blockIdx.x;
    const int tid = threadIdx.x;
    const int w = tid >> 6, lane = tid & 63;
    const float top_p = top_ps[row];

    __shared__ __align__(16) unsigned int sfx[NBIN + 4]; // sfx[b] = count in bins >= b
    __shared__ __align__(16) unsigned int cnt[NBIN];     // arrival counters
    __shared__ __align__(16) unsigned long long skey[2048];  // bin-grouped candidates
    __shared__ __align__(16) unsigned long long srt[1024];   // exact ranks 0..1023
    __shared__ __align__(16) float pv[1024];
    __shared__ __align__(16) float cdf[1024];
    __shared__ unsigned int wsum[16];
    __shared__ int sA[16], sB[16], sC[16];
    __shared__ double sD[16];
    __shared__ int s_R, s_M, s_Kp;
    __shared__ float s_tgt, s_thr, s_pcut, s_logzp;

    // ---- prefetch this row's candidate keys into registers (hides global latency
    // under phase A's ghist suffix-scan) ----
    const int n = min(cntv[row], 2048);
    const unsigned long long* crow = cand + (size_t)row * 2048;
    unsigned long long pk0 = (tid < n) ? crow[tid] : ~0ull;
    unsigned long long pk1 = (tid + 1024 < n) ? crow[tid + 1024] : ~0ull;

    // ---- phase A: suffix-sum of merged histogram into LDS (8 bins/thread) ----
    unsigned int bins[8] = {0, 0, 0, 0, 0, 0, 0, 0};
    #pragma unroll
    for (int c = 0; c < NCHH; ++c) {
        const unsigned int* h = ghist + ((size_t)row * NCHH + c) * NBIN + tid * 8;
        uint4 a0 = *(const uint4*)h, a1 = *(const uint4*)(h + 4);
        bins[0] += a0.x; bins[1] += a0.y; bins[2] += a0.z; bins[3] += a0.w;
        bins[4] += a1.x; bins[5] += a1.y; bins[6] += a1.z; bins[7] += a1.w;
    }
    unsigned int lsfx[8];                // local suffix within my 8 bins
    lsfx[7] = bins[7];
    #pragma unroll
    for (int b = 6; b >= 0; --b) lsfx[b] = bins[b] + lsfx[b + 1];
    const unsigned int s8 = lsfx[0];

    unsigned int v = s8;
    #pragma unroll
    for (int off = 1; off < 64; off <<= 1) {
        unsigned int o = __shfl_down(v, off);
        v += (lane + off < 64) ? o : 0u;
    }
    if (lane == 0) wsum[w] = v;
    __syncthreads();
    unsigned int above = 0;
    for (int ww = w + 1; ww < 16; ++ww) above += wsum[ww];
    const unsigned int thr_above = (v + above) - s8;   // count strictly above my bins
    {
        uint4 o0 = make_uint4(thr_above + lsfx[0], thr_above + lsfx[1],
                              thr_above + lsfx[2], thr_above + lsfx[3]);
        uint4 o1 = make_uint4(thr_above + lsfx[4], thr_above + lsfx[5],
                              thr_above + lsfx[6], thr_above + lsfx[7]);
        *(uint4*)&sfx[tid * 8] = o0;
        *(uint4*)&sfx[tid * 8 + 4] = o1;
        *(uint4*)&cnt[tid * 8] = make_uint4(0, 0, 0, 0);
        *(uint4*)&cnt[tid * 8 + 4] = make_uint4(0, 0, 0, 0);
    }
    if (tid == 0) sfx[NBIN] = 0;
    __syncthreads();

    // ---- placement: slot = rank-base of bin + arrival offset (dense [0,n)) ----
    #pragma unroll
    for (int q = 0; q < 2; ++q) {
        unsigned long long k = q ? pk1 : pk0;
        if (tid + q * 1024 < n) {
            int b = key_b(k);
            unsigned int off = atomicAdd(&cnt[b], 1u);
            unsigned int slot = sfx[b + 1] + off;
            if (slot < 2048u) skey[slot] = k;
        }
    }
    __syncthreads();

    // ---- within-bin exact ranking; skip segments at rank>=1024; singleton fast path ----
    #pragma unroll
    for (int q = 0; q < 2; ++q) {
        const int s = tid + q * 1024;
        if (s < n) {
            unsigned long long k = skey[s];
            int b = key_b(k);
            int lo = (int)sfx[b + 1];
            if (lo < 1024) {
                int hi = (int)sfx[b]; if (hi > n) hi = n;
                if (hi - lo == 1) {
                    srt[lo] = k; pv[lo] = key_p(k);
                } else {
                    int r = lo;
                    for (int j = lo; j < hi; ++j) r += (skey[j] < k);
                    if (r < 1024) { srt[r] = k; pv[r] = key_p(k); }
                }
            }
        }
    }
    __syncthreads();

    // ---- serial exact f32 cumsum (matches ref order) ----
    if (tid == 0) {
        float s = 0.f;
        for (int j = 0; j < 1024; j += 8) {
            float4 q0 = *(const float4*)&pv[j];
            float4 q1 = *(const float4*)&pv[j + 4];
            s += q0.x; cdf[j + 0] = s;
            s += q0.y; cdf[j + 1] = s;
            s += q0.z; cdf[j + 2] = s;
            s += q0.w; cdf[j + 3] = s;
            s += q1.x; cdf[j + 4] = s;
            s += q1.y; cdf[j + 5] = s;
            s += q1.z; cdf[j + 6] = s;
            s += q1.w; cdf[j + 7] = s;
        }
        s_thr = pv[0] * min_ps[row];
    }
    __syncthreads();

    // ---- crossing rank R and min-p cut M via ballot + wave-0 shfl reduce ----
    {
        float p = pv[tid];
        float a = cdf[tid] - p;                        // == ref csum - probs_sort
        unsigned long long bx = __ballot(a > top_p);   // excluded by top-p
        unsigned long long bm = __ballot(p < s_thr);   // below min-p threshold
        if (lane == 0) {
            sA[w] = bx ? (w * 64 + __builtin_ctzll(bx)) : (1 << 30);
            sB[w] = bm ? (w * 64 + __builtin_ctzll(bm)) : (1 << 30);
        }
    }
    __syncthreads();
    if (w == 0) {
        int a = (lane < 16) ? sA[lane] : (1 << 30);
        int b2 = (lane < 16) ? sB[lane] : (1 << 30);
        #pragma unroll
        for (int off = 8; off > 0; off >>= 1) {
            a = min(a, __shfl_down(a, off));
            b2 = min(b2, __shfl_down(b2, off));
        }
        if (lane == 0) { s_R = a; s_M = b2; }
    }
    __syncthreads();

    const int R = s_R;
    const int Reff = (R <= 1023) ? R : 1024;

    // ---- zp mass: f64 parallel sum of pv[0..Reff) ----
    {
        double zc = (tid < Reff) ? (double)pv[tid] : 0.0;
        for (int off = 32; off > 0; off >>= 1) zc += __shfl_down(zc, off);
        if (lane == 0) sD[w] = zc;
    }
    __syncthreads();
    if (w == 0) {
        double z = (lane < 16) ? sD[lane] : 0.0;
        #pragma unroll
        for (int off = 8; off > 0; off >>= 1) z += __shfl_down(z, off);
        if (lane == 0) {
            float zpv;
            if (R <= 1023)               zpv = (float)z;   // exact kept mass
            else if (cdf[1023] > top_p)  zpv = (float)z;   // rank-1024 crossing
            else                         zpv = top_p;      // beyond 1024: zp in (top_p, top_p+1e-3]
            s_pcut  = pv[Reff - 1];
            s_logzp = logf(zpv);

            int K = top_ks[row]; if (Reff < K) K = Reff; if (K > 1024) K = 1024;
            int Kp = (s_M < K) ? s_M : K;                  // min-p suffix cut (Kp >= 1)
            s_Kp = Kp;
            s_tgt = u_arr[row] * cdf[Kp - 1];              // u * cdf[-1], f32
        }
    }
    __syncthreads();

    // ---- parallel count of (cdf < target) ----
    {
        const int Kp = s_Kp; const float tgt = s_tgt;
        bool lt = (tid < Kp) && (cdf[tid] < tgt);
        unsigned long long bc = __ballot(lt);
        if (lane == 0) sC[w] = __popcll(bc);
    }
    __syncthreads();

    // ---- scatter kept logprobs from the (bin-grouped, unsorted) candidate list ----
    {
        const float pcut = s_pcut, logzp = s_logzp;
        for (int i = tid; i < n; i += 1024) {
            unsigned long long k = skey[i];
            float p = key_p(k);
            if (p >= pcut) {
                float val = __logf(p) - logzp;
                if (!(val >= BF16_LO)) val = BF16_LO;  // kills -inf / NaN
                d_out[BB + (size_t)row * VV + key_i(k)] = __float2bfloat16(val);
            }
        }
    }
    if (w == 0) {
        int c2 = (lane < 16) ? sC[lane] : 0;
        #pragma unroll
        for (int off = 8; off > 0; off >>= 1) c2 += __shfl_down(c2, off);
        if (lane == 0) {
            const unsigned long long ktok = srt[c2];   // c2 <= Kp-1 <= 1023
            const int token = key_i(ktok);
            d_out[row] = __float2bfloat16((float)token);   // token id (bf16 out)
            float tval = __logf(key_p(ktok)) - s_logzp;    // token always kept
            if (!(tval >= BF16_LO)) tval = BF16_LO;
            d_out[(size_t)BB * VV + BB + row] = __float2bfloat16(tval);
        }
    }
}

// ---------------- host ----------------
extern "C" void kernel_launch(void* const* d_in, const int* in_sizes, int n_in,
                              void* d_out, int out_size, void* d_ws, size_t ws_size,
                              hipStream_t stream) {
    const float* logits = (const float*)d_in[0];
    const float* temps  = (const float*)d_in[1];
    const int*   top_ks = (const int*)d_in[2];
    const float* top_ps = (const float*)d_in[3];
    const float* min_ps = (const float*)d_in[4];
    const float* u      = (const float*)d_in[5];
    __hip_bfloat16* out = (__hip_bfloat16*)d_out;

    char* wsb = (char*)d_ws;
    unsigned int* ghist = (unsigned int*)wsb;                       // 16 MiB (4 partials/row)
    float* zpart  = (float*)(wsb + (size_t)BB * NCHH * NBIN * 4);   // 512 f32
    float* Zv     = zpart + BB * NCHH;
    unsigned int* tv = (unsigned int*)(Zv + BB);
    int* cntv     = (int*)(tv + BB);
    unsigned long long* cand =
        (unsigned long long*)(wsb + ((size_t)BB * NCHH * NBIN * 4 + 65536)); // 2 MiB

    k_hist<<<dim3(NCHH, BB), 1024, 0, stream>>>(logits, temps, ghist, zpart);
    k_thresh<<<BB, 1024, 0, stream>>>(ghist, zpart, Zv, tv, cntv);
    k_gather<<<dim3(NCHG, BB), 256, 0, stream>>>(logits, temps, Zv, tv, cntv, cand, out);
    k_sample<<<BB, 1024, 0, stream>>>(cand, cntv, ghist, top_ks, top_ps, min_ps, u, out);
}

// Round 10
// 157.598 us; speedup vs baseline: 1.3683x; 1.0322x over previous
//
#include <hip/hip_runtime.h>
#include <hip/hip_bf16.h>

#define BB 128
#define VV 128000
#define NCHH 4                  // hist chunks/row (partial hists, no atomics)
#define CHH (VV / NCHH)         // 32000
#define NBIN 8192               // fx >> 19
#define HPAD 16                 // bank-shift pad between the 2 LDS hist copies
#define CEXP 16.0f              // fixed softmax scale: l/T in [-20,20] -> exp arg in [-36,4]
static constexpr float BF16_LO = -3.3e38f;   // finite in bf16 (max bf16 = 3.3895e38)
static_assert(VV < (1 << 17), "idx must fit 17 bits");
static_assert((CHH % 8) == 0 && (VV % 8) == 0, "vector passes");

__device__ __forceinline__ unsigned int flip_f(unsigned int b) {
    return b ^ ((b & 0x80000000u) ? 0xFFFFFFFFu : 0x80000000u);
}
// key layout: [63:49] = 8191-bin (order-consistent tag), [48:17] = ~p_bits, [16:0] = idx
__device__ __forceinline__ float key_p(unsigned long long k) {
    return __uint_as_float(~(unsigned int)(k >> 17));   // truncation keeps bits 17..48
}
__device__ __forceinline__ int key_i(unsigned long long k) {
    return (int)(k & 0x1FFFFull);
}
__device__ __forceinline__ int key_b(unsigned long long k) {
    return 8191 - (int)(k >> 49);
}

// ---------------- K1: partial histograms (2 lane-parity LDS copies, bank-shifted)
// + Z partials ----------------
__global__ __launch_bounds__(1024) void k_hist(
    const float* __restrict__ logits, const float* __restrict__ temps,
    unsigned int* __restrict__ ghist, float* __restrict__ zpart)
{
    const int row = blockIdx.y, chunk = blockIdx.x;
    const int tid = threadIdx.x;
    const int w = tid >> 6, lane = tid & 63;
    const float rT = 1.0f / temps[row];

    __shared__ unsigned int hist[2 * (NBIN + HPAD)];  // copy by LANE parity
    __shared__ float red[16];

    for (int j = tid; j < 2 * (NBIN + HPAD); j += 1024) hist[j] = 0;
    unsigned int* myh = hist + (lane & 1) * (NBIN + HPAD);
    __syncthreads();

    // main loop: 1-ahead register prefetch (2 blocks/CU + ILP hide HBM latency)
    const float4* lp4 = (const float4*)(logits + (size_t)row * VV + (size_t)chunk * CHH);
    const int N4 = CHH / 4;
    float zs = 0.f;
    int i = tid;
    bool have = i < N4;
    float4 cur = have ? lp4[i] : make_float4(0.f, 0.f, 0.f, 0.f);
    while (have) {
        const int inext = i + 1024;
        const bool hnext = inext < N4;
        float4 nxt = hnext ? lp4[inext] : make_float4(0.f, 0.f, 0.f, 0.f);
        float e4[4] = {cur.x, cur.y, cur.z, cur.w};
        #pragma unroll
        for (int e = 0; e < 4; ++e) {
            atomicAdd(&myh[flip_f(__float_as_uint(e4[e])) >> 19], 1u);  // LDS atomic
            zs += __expf(fmaf(e4[e], rT, -CEXP));
        }
        cur = nxt; i = inext; have = hnext;
    }
    #pragma unroll
    for (int off = 32; off > 0; off >>= 1) zs += __shfl_down(zs, off);
    if (lane == 0) red[w] = zs;
    __syncthreads();

    // merge copies, publish disjoint partial (plain coalesced stores)
    unsigned int* gh = ghist + ((size_t)row * NCHH + chunk) * NBIN;
    for (int j = tid; j < NBIN; j += 1024) gh[j] = hist[j] + hist[NBIN + HPAD + j];
    if (tid == 0) {
        float z = 0.f;
        #pragma unroll
        for (int i2 = 0; i2 < 16; ++i2) z += red[i2];
        zpart[row * NCHH + chunk] = z;
    }
}

// ---------------- K2: per-row fused thresh + gather-with-placement + rank + sample
// + scatter. One sfx scan yields threshold, candidate count, AND counting-sort bases.
// No cand/cntv globals; fill issued fire-and-forget under the gather loop. ----------------
__global__ __launch_bounds__(1024) void k_row(
    const float* __restrict__ logits, const float* __restrict__ temps,
    const unsigned int* __restrict__ ghist, const float* __restrict__ zpart,
    const int* __restrict__ top_ks, const float* __restrict__ top_ps,
    const float* __restrict__ min_ps, const float* __restrict__ u_arr,
    __hip_bfloat16* __restrict__ d_out)
{
    const int row = blockIdx.x;
    const int tid = threadIdx.x;
    const int w = tid >> 6, lane = tid & 63;
    const float top_p = top_ps[row];

    __shared__ __align__(16) unsigned int sfx[NBIN + 4]; // sfx[b] = count in bins >= b
    __shared__ __align__(16) unsigned int cnt[NBIN];     // arrival counters
    __shared__ __align__(16) unsigned long long skey[2048];  // bin-grouped candidates
    __shared__ __align__(16) unsigned long long srt[1024];   // exact ranks 0..1023
    __shared__ __align__(16) float pv[1024];
    __shared__ __align__(16) float cdf[1024];
    __shared__ unsigned int wsum[16];
    __shared__ int sA[16], sB[16], sC[16];
    __shared__ double sD[16];
    __shared__ int s_bsel, s_R, s_M, s_Kp;
    __shared__ float s_tgt, s_thr, s_pcut, s_logzp;

    // ---- phase A: suffix-sum of merged histogram -> sfx (also zeroes cnt) ----
    unsigned int bins[8] = {0, 0, 0, 0, 0, 0, 0, 0};
    #pragma unroll
    for (int c = 0; c < NCHH; ++c) {
        const unsigned int* h = ghist + ((size_t)row * NCHH + c) * NBIN + tid * 8;
        uint4 a0 = *(const uint4*)h, a1 = *(const uint4*)(h + 4);
        bins[0] += a0.x; bins[1] += a0.y; bins[2] += a0.z; bins[3] += a0.w;
        bins[4] += a1.x; bins[5] += a1.y; bins[6] += a1.z; bins[7] += a1.w;
    }
    unsigned int lsfx[8];                // local suffix within my 8 bins
    lsfx[7] = bins[7];
    #pragma unroll
    for (int b = 6; b >= 0; --b) lsfx[b] = bins[b] + lsfx[b + 1];
    const unsigned int s8 = lsfx[0];

    unsigned int v = s8;                 // wave-inclusive suffix sum over lanes
    #pragma unroll
    for (int off = 1; off < 64; off <<= 1) {
        unsigned int o = __shfl_down(v, off);
        v += (lane + off < 64) ? o : 0u;
    }
    if (lane == 0) wsum[w] = v;
    __syncthreads();
    unsigned int above = 0;
    for (int ww = w + 1; ww < 16; ++ww) above += wsum[ww];
    const unsigned int thr_above = (v + above) - s8;   // count strictly above my bins
    {
        uint4 o0 = make_uint4(thr_above + lsfx[0], thr_above + lsfx[1],
                              thr_above + lsfx[2], thr_above + lsfx[3]);
        uint4 o1 = make_uint4(thr_above + lsfx[4], thr_above + lsfx[5],
                              thr_above + lsfx[6], thr_above + lsfx[7]);
        *(uint4*)&sfx[tid * 8] = o0;
        *(uint4*)&sfx[tid * 8 + 4] = o1;
        *(uint4*)&cnt[tid * 8] = make_uint4(0, 0, 0, 0);
        *(uint4*)&cnt[tid * 8 + 4] = make_uint4(0, 0, 0, 0);
    }
    if (tid == 0) sfx[NBIN] = 0;
    __syncthreads();

    // bsel = max b with sfx[b] >= 1024 (exactly one b satisfies the crossing)
    #pragma unroll
    for (int b2 = 0; b2 < 8; ++b2) {
        const int b = tid * 8 + b2;
        if (sfx[b] >= 1024u && sfx[b + 1] < 1024u) s_bsel = b;
    }
    __syncthreads();
    const int bsel = s_bsel;
    const unsigned int t = ((unsigned int)bsel) << 19;
    const int n = min((int)sfx[bsel], 2048);     // exact candidate count, >= 1024

    // ---- phase B: fill issue (fire-and-forget; drains under gather) ----
    {
        __hip_bfloat16 hlo = __float2bfloat16(BF16_LO);
        unsigned int pat = ((unsigned int)*(unsigned short*)&hlo) * 0x10001u;
        uint4 fv = make_uint4(pat, pat, pat, pat);
        uint4* dst = (uint4*)(d_out + BB + (size_t)row * VV);
        for (int j = tid; j < VV / 8; j += 1024) dst[j] = fv;   // 8 bf16 / store
    }

    // ---- gather fused with counting-sort placement (4-deep load batching) ----
    const float rT = 1.0f / temps[row];
    const float Z = zpart[row * NCHH + 0] + zpart[row * NCHH + 1]
                  + zpart[row * NCHH + 2] + zpart[row * NCHH + 3];
    const float invZ = 1.0f / Z;
    const float4* lp4 = (const float4*)(logits + (size_t)row * VV);
    const int N4 = VV / 4;               // 32000
    for (int i0 = tid; i0 < N4; i0 += 4096) {
        const int i1 = i0 + 1024, i2 = i0 + 2048, i3 = i0 + 3072;
        const bool h1 = i1 < N4, h2 = i2 < N4, h3 = i3 < N4;
        float4 v0 = lp4[i0];             // 4 independent loads in flight
        float4 v1 = h1 ? lp4[i1] : make_float4(0.f, 0.f, 0.f, 0.f);
        float4 v2 = h2 ? lp4[i2] : make_float4(0.f, 0.f, 0.f, 0.f);
        float4 v3 = h3 ? lp4[i3] : make_float4(0.f, 0.f, 0.f, 0.f);
        #pragma unroll
        for (int q = 0; q < 4; ++q) {
            const bool hv = (q == 0) || (q == 1 ? h1 : (q == 2 ? h2 : h3));
            if (!hv) continue;
            const float4 vv = (q == 0) ? v0 : (q == 1 ? v1 : (q == 2 ? v2 : v3));
            const int base4 = (q == 0) ? i0 : (q == 1 ? i1 : (q == 2 ? i2 : i3));
            float e4[4] = {vv.x, vv.y, vv.z, vv.w};
            #pragma unroll
            for (int e = 0; e < 4; ++e) {
                unsigned int fx = flip_f(__float_as_uint(e4[e]));
                if (fx >= t) {
                    float p = __expf(fmaf(e4[e], rT, -CEXP)) * invZ;
                    const int b = (int)(fx >> 19);
                    unsigned int off = atomicAdd(&cnt[b], 1u);   // LDS atomic
                    unsigned int slot = sfx[b + 1] + off;
                    if (slot < 2048u)
                        skey[slot] = (((unsigned long long)(8191 - b)) << 49)
                                   | ((unsigned long long)(~__float_as_uint(p)) << 17)
                                   | (unsigned long long)(base4 * 4 + e);
                }
            }
        }
    }
    __syncthreads();

    // ---- within-bin exact ranking; skip segments at rank>=1024; singleton fast path ----
    #pragma unroll
    for (int q = 0; q < 2; ++q) {
        const int s = tid + q * 1024;
        if (s < n) {
            unsigned long long k = skey[s];
            int b = key_b(k);
            int lo = (int)sfx[b + 1];
            if (lo < 1024) {
                int hi = (int)sfx[b]; if (hi > n) hi = n;
                if (hi - lo == 1) {
                    srt[lo] = k; pv[lo] = key_p(k);
                } else {
                    int r = lo;
                    for (int j = lo; j < hi; ++j) r += (skey[j] < k);
                    if (r < 1024) { srt[r] = k; pv[r] = key_p(k); }
                }
            }
        }
    }
    __syncthreads();

    // ---- serial exact f32 cumsum (matches ref order) ----
    if (tid == 0) {
        float s = 0.f;
        for (int j = 0; j < 1024; j += 8) {
            float4 q0 = *(const float4*)&pv[j];
            float4 q1 = *(const float4*)&pv[j + 4];
            s += q0.x; cdf[j + 0] = s;
            s += q0.y; cdf[j + 1] = s;
            s += q0.z; cdf[j + 2] = s;
            s += q0.w; cdf[j + 3] = s;
            s += q1.x; cdf[j + 4] = s;
            s += q1.y; cdf[j + 5] = s;
            s += q1.z; cdf[j + 6] = s;
            s += q1.w; cdf[j + 7] = s;
        }
        s_thr = pv[0] * min_ps[row];
    }
    __syncthreads();

    // ---- crossing rank R and min-p cut M via ballot + wave-0 shfl reduce ----
    {
        float p = pv[tid];
        float a = cdf[tid] - p;                        // == ref csum - probs_sort
        unsigned long long bx = __ballot(a > top_p);   // excluded by top-p
        unsigned long long bm = __ballot(p < s_thr);   // below min-p threshold
        if (lane == 0) {
            sA[w] = bx ? (w * 64 + __builtin_ctzll(bx)) : (1 << 30);
            sB[w] = bm ? (w * 64 + __builtin_ctzll(bm)) : (1 << 30);
        }
    }
    __syncthreads();
    if (w == 0) {
        int a = (lane < 16) ? sA[lane] : (1 << 30);
        int b2 = (lane < 16) ? sB[lane] : (1 << 30);
        #pragma unroll
        for (int off = 8; off > 0; off >>= 1) {
            a = min(a, __shfl_down(a, off));
            b2 = min(b2, __shfl_down(b2, off));
        }
        if (lane == 0) { s_R = a; s_M = b2; }
    }
    __syncthreads();

    const int R = s_R;
    const int Reff = (R <= 1023) ? R : 1024;

    // ---- zp mass: f64 parallel sum of pv[0..Reff) ----
    {
        double zc = (tid < Reff) ? (double)pv[tid] : 0.0;
        for (int off = 32; off > 0; off >>= 1) zc += __shfl_down(zc, off);
        if (lane == 0) sD[w] = zc;
    }
    __syncthreads();
    if (w == 0) {
        double z = (lane < 16) ? sD[lane] : 0.0;
        #pragma unroll
        for (int off = 8; off > 0; off >>= 1) z += __shfl_down(z, off);
        if (lane == 0) {
            float zpv;
            if (R <= 1023)               zpv = (float)z;   // exact kept mass
            else if (cdf[1023] > top_p)  zpv = (float)z;   // rank-1024 crossing
            else                         zpv = top_p;      // beyond 1024: zp in (top_p, top_p+1e-3]
            s_pcut  = pv[Reff - 1];
            s_logzp = logf(zpv);

            int K = top_ks[row]; if (Reff < K) K = Reff; if (K > 1024) K = 1024;
            int Kp = (s_M < K) ? s_M : K;                  // min-p suffix cut (Kp >= 1)
            s_Kp = Kp;
            s_tgt = u_arr[row] * cdf[Kp - 1];              // u * cdf[-1], f32
        }
    }
    __syncthreads();

    // ---- parallel count of (cdf < target) ----
    {
        const int Kp = s_Kp; const float tgt = s_tgt;
        bool lt = (tid < Kp) && (cdf[tid] < tgt);
        unsigned long long bc = __ballot(lt);
        if (lane == 0) sC[w] = __popcll(bc);
    }
    __syncthreads();

    // ---- scatter kept logprobs from the (bin-grouped, unsorted) candidate list.
    // Fill stores above are guaranteed complete (vmcnt-drained at earlier barriers),
    // and fill/scatter touch only this block's own row -> race-free. ----
    {
        const float pcut = s_pcut, logzp = s_logzp;
        for (int i = tid; i < n; i += 1024) {
            unsigned long long k = skey[i];
            float p = key_p(k);
            if (p >= pcut) {
                float val = __logf(p) - logzp;
                if (!(val >= BF16_LO)) val = BF16_LO;  // kills -inf / NaN
                d_out[BB + (size_t)row * VV + key_i(k)] = __float2bfloat16(val);
            }
        }
    }
    if (w == 0) {
        int c2 = (lane < 16) ? sC[lane] : 0;
        #pragma unroll
        for (int off = 8; off > 0; off >>= 1) c2 += __shfl_down(c2, off);
        if (lane == 0) {
            const unsigned long long ktok = srt[c2];   // c2 <= Kp-1 <= 1023
            const int token = key_i(ktok);
            d_out[row] = __float2bfloat16((float)token);   // token id (bf16 out)
            float tval = __logf(key_p(ktok)) - s_logzp;    // token always kept
            if (!(tval >= BF16_LO)) tval = BF16_LO;
            d_out[(size_t)BB * VV + BB + row] = __float2bfloat16(tval);
        }
    }
}

// ---------------- host ----------------
extern "C" void kernel_launch(void* const* d_in, const int* in_sizes, int n_in,
                              void* d_out, int out_size, void* d_ws, size_t ws_size,
                              hipStream_t stream) {
    const float* logits = (const float*)d_in[0];
    const float* temps  = (const float*)d_in[1];
    const int*   top_ks = (const int*)d_in[2];
    const float* top_ps = (const float*)d_in[3];
    const float* min_ps = (const float*)d_in[4];
    const float* u      = (const float*)d_in[5];
    __hip_bfloat16* out = (__hip_bfloat16*)d_out;

    char* wsb = (char*)d_ws;
    unsigned int* ghist = (unsigned int*)wsb;                       // 16 MiB (4 partials/row)
    float* zpart  = (float*)(wsb + (size_t)BB * NCHH * NBIN * 4);   // 512 f32

    k_hist<<<dim3(NCHH, BB), 1024, 0, stream>>>(logits, temps, ghist, zpart);
    k_row<<<BB, 1024, 0, stream>>>(logits, temps, ghist, zpart,
                                   top_ks, top_ps, min_ps, u, out);
}

// Round 11
// 151.473 us; speedup vs baseline: 1.4236x; 1.0404x over previous
//
#include <hip/hip_runtime.h>
#include <hip/hip_bf16.h>

#define BB 128
#define VV 128000
#define NCHH 4                  // hist chunks/row
#define CHH (VV / NCHH)         // 32000
#define NBIN 8192               // fx >> 19
#define HPAD 16                 // bank-shift pad between the 2 LDS hist copies
#define CCAP 2048               // per-chunk candidate capacity (superset list)
#define CEXP 16.0f              // fixed softmax scale: l/T in [-20,20] -> exp arg in [-36,4]
static constexpr float BF16_LO = -3.3e38f;   // finite in bf16 (max bf16 = 3.3895e38)
static_assert(VV < (1 << 17), "idx must fit 17 bits");
static_assert((CHH % 8) == 0, "vector passes");

__device__ __forceinline__ unsigned int flip_f(unsigned int b) {
    return b ^ ((b & 0x80000000u) ? 0xFFFFFFFFu : 0x80000000u);
}
__device__ __forceinline__ unsigned int unflip_f(unsigned int fx) {
    return (fx >= 0x80000000u) ? (fx ^ 0x80000000u) : ~fx;
}
// final sort key: [63:49] = 8191-bin, [48:17] = ~p_bits, [16:0] = idx (asc = p desc, idx asc)
__device__ __forceinline__ float key_p(unsigned long long k) {
    return __uint_as_float(~(unsigned int)(k >> 17));
}
__device__ __forceinline__ int key_i(unsigned long long k) {
    return (int)(k & 0x1FFFFull);
}
__device__ __forceinline__ int key_b(unsigned long long k) {
    return 8191 - (int)(k >> 49);
}

// ---------------- K1: per-chunk histogram (2 lane-parity LDS copies) + Z partial
// + LOCAL rank-1024 threshold t_c (<= global t) + superset candidate emit (fx,idx)
// from the L2-hot chunk re-scan + BF16_LO fill of the chunk's logprob slice ----------------
__global__ __launch_bounds__(1024) void k_hist(
    const float* __restrict__ logits, const float* __restrict__ temps,
    unsigned long long* __restrict__ cand, int* __restrict__ cntc,
    float* __restrict__ zpart, __hip_bfloat16* __restrict__ d_out)
{
    const int row = blockIdx.y, chunk = blockIdx.x;
    const int tid = threadIdx.x;
    const int w = tid >> 6, lane = tid & 63;
    const float rT = 1.0f / temps[row];

    __shared__ __align__(16) unsigned int hist[2 * (NBIN + HPAD)];
    __shared__ float red[16];
    __shared__ unsigned int wsum[16];
    __shared__ int wcnt[16];
    __shared__ unsigned int s_t;
    __shared__ int s_n;
    // after the merge, the second hist copy's storage is reused as the candidate buffer
    unsigned long long* lbuf = (unsigned long long*)&hist[NBIN + HPAD];  // 16 KB < 32.8 KB

    for (int j = tid; j < 2 * (NBIN + HPAD); j += 1024) hist[j] = 0;
    unsigned int* myh = hist + (lane & 1) * (NBIN + HPAD);
    __syncthreads();

    // main loop: 1-ahead register prefetch (2 blocks/CU + ILP hide HBM latency)
    const float4* lp4 = (const float4*)(logits + (size_t)row * VV + (size_t)chunk * CHH);
    const int N4 = CHH / 4;
    float zs = 0.f;
    int i = tid;
    bool have = i < N4;
    float4 cur = have ? lp4[i] : make_float4(0.f, 0.f, 0.f, 0.f);
    while (have) {
        const int inext = i + 1024;
        const bool hnext = inext < N4;
        float4 nxt = hnext ? lp4[inext] : make_float4(0.f, 0.f, 0.f, 0.f);
        float e4[4] = {cur.x, cur.y, cur.z, cur.w};
        #pragma unroll
        for (int e = 0; e < 4; ++e) {
            atomicAdd(&myh[flip_f(__float_as_uint(e4[e])) >> 19], 1u);  // LDS atomic
            zs += __expf(fmaf(e4[e], rT, -CEXP));
        }
        cur = nxt; i = inext; have = hnext;
    }
    #pragma unroll
    for (int off = 32; off > 0; off >>= 1) zs += __shfl_down(zs, off);
    if (lane == 0) red[w] = zs;
    __syncthreads();

    // merge the 2 copies into hist[0..NBIN)
    for (int j = tid; j < NBIN; j += 1024) hist[j] = hist[j] + hist[NBIN + HPAD + j];
    if (tid == 0) {
        float z = 0.f;
        #pragma unroll
        for (int i2 = 0; i2 < 16; ++i2) z += red[i2];
        zpart[row * NCHH + chunk] = z;
        s_n = 0;
    }
    __syncthreads();

    // local rank-1024 threshold (suffix-scan of the LOCAL chunk hist)
    unsigned int bins[8];
    {
        uint4 a0 = *(const uint4*)&hist[tid * 8], a1 = *(const uint4*)&hist[tid * 8 + 4];
        bins[0] = a0.x; bins[1] = a0.y; bins[2] = a0.z; bins[3] = a0.w;
        bins[4] = a1.x; bins[5] = a1.y; bins[6] = a1.z; bins[7] = a1.w;
    }
    unsigned int s8 = 0;
    #pragma unroll
    for (int b = 0; b < 8; ++b) s8 += bins[b];
    unsigned int v = s8;
    #pragma unroll
    for (int off = 1; off < 64; off <<= 1) {
        unsigned int o = __shfl_down(v, off);
        v += (lane + off < 64) ? o : 0u;
    }
    if (lane == 0) wsum[w] = v;
    __syncthreads();
    unsigned int above = 0;
    for (int ww = w + 1; ww < 16; ++ww) above += wsum[ww];
    const unsigned int S = v + above;    // local count in bins >= tid*8
    {
        unsigned long long bge = __ballot(S >= 1024u);
        if (lane == 0) wcnt[w] = __popcll(bge);
    }
    __syncthreads();
    {
        int tc = -1;
        for (int ww = 0; ww < 16; ++ww) tc += wcnt[ww];   // crossing thread
        if (tid == tc) {
            unsigned int acc = S - s8;
            int bsel = -1;
            #pragma unroll
            for (int b = 7; b >= 0; --b) {   // register-only, no break
                acc += bins[b];
                if (bsel < 0 && acc >= 1024u) bsel = tid * 8 + b;
            }
            s_t = ((unsigned int)bsel) << 19;
        }
    }
    __syncthreads();

    // re-scan the (L2/L3-hot) chunk; emit (fx,idx) superset candidates
    const unsigned int t = s_t;
    for (int j = tid; j < N4; j += 1024) {
        float4 vv = lp4[j];
        float e4[4] = {vv.x, vv.y, vv.z, vv.w};
        #pragma unroll
        for (int e = 0; e < 4; ++e) {
            unsigned int fx = flip_f(__float_as_uint(e4[e]));
            if (fx >= t) {
                int pos = atomicAdd(&s_n, 1);
                if (pos < CCAP)
                    lbuf[pos] = ((unsigned long long)fx << 17)
                              | (unsigned long long)(chunk * CHH + j * 4 + e);
            }
        }
    }
    __syncthreads();
    const int n = (s_n < CCAP) ? s_n : CCAP;
    if (tid == 0) cntc[row * NCHH + chunk] = n;
    unsigned long long* gc = cand + ((size_t)row * NCHH + chunk) * CCAP;
    for (int j = tid; j < n; j += 1024) gc[j] = lbuf[j];

    // tail fill of this chunk's logprob slice: drains at retire (no barrier after)
    {
        __hip_bfloat16 hlo = __float2bfloat16(BF16_LO);
        unsigned int pat = ((unsigned int)*(unsigned short*)&hlo) * 0x10001u;
        uint4 fv = make_uint4(pat, pat, pat, pat);
        uint4* dst = (uint4*)(d_out + BB + (size_t)row * VV + (size_t)chunk * CHH);
        for (int j = tid; j < CHH / 8; j += 1024) dst[j] = fv;   // 8 bf16 / store
    }
}

// ---------------- K2: per-row sample from candidate lists only (no logits/ghist reads).
// Union-hist -> global bsel (exact: every chunk kept all bins >= its t_c <= bsel),
// counting-sort placement with bit-identical keys, ranking, cumsum, cuts, scatter. ----------------
__global__ __launch_bounds__(1024) void k_row(
    const unsigned long long* __restrict__ cand, const int* __restrict__ cntc,
    const float* __restrict__ temps, const float* __restrict__ zpart,
    const int* __restrict__ top_ks, const float* __restrict__ top_ps,
    const float* __restrict__ min_ps, const float* __restrict__ u_arr,
    __hip_bfloat16* __restrict__ d_out)
{
    const int row = blockIdx.x;
    const int tid = threadIdx.x;
    const int w = tid >> 6, lane = tid & 63;
    const float top_p = top_ps[row];

    __shared__ __align__(16) unsigned int sfx[NBIN + 4]; // sfx[b] = union count in bins >= b
    __shared__ __align__(16) unsigned int cnt[NBIN];     // hist, then arrival counters
    __shared__ __align__(16) unsigned long long skey[2048];
    __shared__ __align__(16) unsigned long long srt[1024];
    __shared__ __align__(16) float pv[1024];
    __shared__ __align__(16) float cdf[1024];
    __shared__ unsigned int wsum[16];
    __shared__ int sA[16], sB[16], sC[16];
    __shared__ double sD[16];
    __shared__ int s_bsel, s_R, s_M, s_Kp;
    __shared__ float s_tgt, s_thr, s_pcut, s_logzp;

    const int nc[4] = {cntc[row * NCHH + 0], cntc[row * NCHH + 1],
                       cntc[row * NCHH + 2], cntc[row * NCHH + 3]};
    for (int j = tid; j < NBIN / 4; j += 1024)
        *(uint4*)&cnt[j * 4] = make_uint4(0, 0, 0, 0);
    __syncthreads();

    // union histogram of candidate bins (bin = fx>>19 = key>>36)
    #pragma unroll
    for (int q = 0; q < NCHH; ++q) {
        const unsigned long long* cq = cand + ((size_t)row * NCHH + q) * CCAP;
        for (int j = tid; j < nc[q]; j += 1024)
            atomicAdd(&cnt[(unsigned int)(cq[j] >> 36)], 1u);
    }
    __syncthreads();

    // suffix-sum -> sfx (exact global counts for all bins >= global bsel)
    unsigned int bins[8];
    {
        uint4 a0 = *(const uint4*)&cnt[tid * 8], a1 = *(const uint4*)&cnt[tid * 8 + 4];
        bins[0] = a0.x; bins[1] = a0.y; bins[2] = a0.z; bins[3] = a0.w;
        bins[4] = a1.x; bins[5] = a1.y; bins[6] = a1.z; bins[7] = a1.w;
    }
    unsigned int lsfx[8];
    lsfx[7] = bins[7];
    #pragma unroll
    for (int b = 6; b >= 0; --b) lsfx[b] = bins[b] + lsfx[b + 1];
    const unsigned int s8 = lsfx[0];
    unsigned int v = s8;
    #pragma unroll
    for (int off = 1; off < 64; off <<= 1) {
        unsigned int o = __shfl_down(v, off);
        v += (lane + off < 64) ? o : 0u;
    }
    if (lane == 0) wsum[w] = v;
    __syncthreads();
    unsigned int above = 0;
    for (int ww = w + 1; ww < 16; ++ww) above += wsum[ww];
    const unsigned int thr_above = (v + above) - s8;
    {
        uint4 o0 = make_uint4(thr_above + lsfx[0], thr_above + lsfx[1],
                              thr_above + lsfx[2], thr_above + lsfx[3]);
        uint4 o1 = make_uint4(thr_above + lsfx[4], thr_above + lsfx[5],
                              thr_above + lsfx[6], thr_above + lsfx[7]);
        *(uint4*)&sfx[tid * 8] = o0;
        *(uint4*)&sfx[tid * 8 + 4] = o1;
        // re-zero cnt for arrival counters (bins already captured in registers)
        *(uint4*)&cnt[tid * 8] = make_uint4(0, 0, 0, 0);
        *(uint4*)&cnt[tid * 8 + 4] = make_uint4(0, 0, 0, 0);
    }
    if (tid == 0) sfx[NBIN] = 0;
    __syncthreads();

    // global crossing bin (unique: sfx is non-increasing)
    #pragma unroll
    for (int b2 = 0; b2 < 8; ++b2) {
        const int b = tid * 8 + b2;
        if (sfx[b] >= 1024u && sfx[b + 1] < 1024u) s_bsel = b;
    }
    __syncthreads();
    const int bsel = s_bsel;
    const int n = min((int)sfx[bsel], 2048);     // exact global candidate count >= 1024

    // placement: filter to bin >= bsel, build bit-identical keys, counting-sort slot
    const float rT = 1.0f / temps[row];
    const float Z = zpart[row * NCHH + 0] + zpart[row * NCHH + 1]
                  + zpart[row * NCHH + 2] + zpart[row * NCHH + 3];
    const float invZ = 1.0f / Z;
    #pragma unroll
    for (int q = 0; q < NCHH; ++q) {
        const unsigned long long* cq = cand + ((size_t)row * NCHH + q) * CCAP;
        for (int j = tid; j < nc[q]; j += 1024) {
            unsigned long long ck = cq[j];
            unsigned int fx = (unsigned int)(ck >> 17);
            const int b = (int)(fx >> 19);
            if (b >= bsel) {
                float l = __uint_as_float(unflip_f(fx));
                float p = __expf(fmaf(l, rT, -CEXP)) * invZ;   // bit-identical to R10
                unsigned int off = atomicAdd(&cnt[b], 1u);
                unsigned int slot = sfx[b + 1] + off;
                if (slot < 2048u)
                    skey[slot] = (((unsigned long long)(8191 - b)) << 49)
                               | ((unsigned long long)(~__float_as_uint(p)) << 17)
                               | (ck & 0x1FFFFull);
            }
        }
    }
    __syncthreads();

    // within-bin exact ranking; skip segments at rank>=1024; singleton fast path
    #pragma unroll
    for (int q = 0; q < 2; ++q) {
        const int s = tid + q * 1024;
        if (s < n) {
            unsigned long long k = skey[s];
            int b = key_b(k);
            int lo = (int)sfx[b + 1];
            if (lo < 1024) {
                int hi = (int)sfx[b]; if (hi > n) hi = n;
                if (hi - lo == 1) {
                    srt[lo] = k; pv[lo] = key_p(k);
                } else {
                    int r = lo;
                    for (int j = lo; j < hi; ++j) r += (skey[j] < k);
                    if (r < 1024) { srt[r] = k; pv[r] = key_p(k); }
                }
            }
        }
    }
    __syncthreads();

    // serial exact f32 cumsum (matches ref order)
    if (tid == 0) {
        float s = 0.f;
        for (int j = 0; j < 1024; j += 8) {
            float4 q0 = *(const float4*)&pv[j];
            float4 q1 = *(const float4*)&pv[j + 4];
            s += q0.x; cdf[j + 0] = s;
            s += q0.y; cdf[j + 1] = s;
            s += q0.z; cdf[j + 2] = s;
            s += q0.w; cdf[j + 3] = s;
            s += q1.x; cdf[j + 4] = s;
            s += q1.y; cdf[j + 5] = s;
            s += q1.z; cdf[j + 6] = s;
            s += q1.w; cdf[j + 7] = s;
        }
        s_thr = pv[0] * min_ps[row];
    }
    __syncthreads();

    // crossing rank R and min-p cut M via ballot + wave-0 shfl reduce
    {
        float p = pv[tid];
        float a = cdf[tid] - p;                        // == ref csum - probs_sort
        unsigned long long bx = __ballot(a > top_p);   // excluded by top-p
        unsigned long long bm = __ballot(p < s_thr);   // below min-p threshold
        if (lane == 0) {
            sA[w] = bx ? (w * 64 + __builtin_ctzll(bx)) : (1 << 30);
            sB[w] = bm ? (w * 64 + __builtin_ctzll(bm)) : (1 << 30);
        }
    }
    __syncthreads();
    if (w == 0) {
        int a = (lane < 16) ? sA[lane] : (1 << 30);
        int b2 = (lane < 16) ? sB[lane] : (1 << 30);
        #pragma unroll
        for (int off = 8; off > 0; off >>= 1) {
            a = min(a, __shfl_down(a, off));
            b2 = min(b2, __shfl_down(b2, off));
        }
        if (lane == 0) { s_R = a; s_M = b2; }
    }
    __syncthreads();

    const int R = s_R;
    const int Reff = (R <= 1023) ? R : 1024;

    // zp mass: f64 parallel sum of pv[0..Reff)
    {
        double zc = (tid < Reff) ? (double)pv[tid] : 0.0;
        for (int off = 32; off > 0; off >>= 1) zc += __shfl_down(zc, off);
        if (lane == 0) sD[w] = zc;
    }
    __syncthreads();
    if (w == 0) {
        double z = (lane < 16) ? sD[lane] : 0.0;
        #pragma unroll
        for (int off = 8; off > 0; off >>= 1) z += __shfl_down(z, off);
        if (lane == 0) {
            float zpv;
            if (R <= 1023)               zpv = (float)z;   // exact kept mass
            else if (cdf[1023] > top_p)  zpv = (float)z;   // rank-1024 crossing
            else                         zpv = top_p;      // beyond 1024
            s_pcut  = pv[Reff - 1];
            s_logzp = logf(zpv);

            int K = top_ks[row]; if (Reff < K) K = Reff; if (K > 1024) K = 1024;
            int Kp = (s_M < K) ? s_M : K;                  // min-p suffix cut (Kp >= 1)
            s_Kp = Kp;
            s_tgt = u_arr[row] * cdf[Kp - 1];              // u * cdf[-1], f32
        }
    }
    __syncthreads();

    // parallel count of (cdf < target)
    {
        const int Kp = s_Kp; const float tgt = s_tgt;
        bool lt = (tid < Kp) && (cdf[tid] < tgt);
        unsigned long long bc = __ballot(lt);
        if (lane == 0) sC[w] = __popcll(bc);
    }
    __syncthreads();

    // scatter kept logprobs (fill done by k_hist; stream-ordered before this kernel)
    {
        const float pcut = s_pcut, logzp = s_logzp;
        for (int i = tid; i < n; i += 1024) {
            unsigned long long k = skey[i];
            float p = key_p(k);
            if (p >= pcut) {
                float val = __logf(p) - logzp;
                if (!(val >= BF16_LO)) val = BF16_LO;  // kills -inf / NaN
                d_out[BB + (size_t)row * VV + key_i(k)] = __float2bfloat16(val);
            }
        }
    }
    if (w == 0) {
        int c2 = (lane < 16) ? sC[lane] : 0;
        #pragma unroll
        for (int off = 8; off > 0; off >>= 1) c2 += __shfl_down(c2, off);
        if (lane == 0) {
            const unsigned long long ktok = srt[c2];   // c2 <= Kp-1 <= 1023
            const int token = key_i(ktok);
            d_out[row] = __float2bfloat16((float)token);   // token id (bf16 out)
            float tval = __logf(key_p(ktok)) - s_logzp;    // token always kept
            if (!(tval >= BF16_LO)) tval = BF16_LO;
            d_out[(size_t)BB * VV + BB + row] = __float2bfloat16(tval);
        }
    }
}

// ---------------- host ----------------
extern "C" void kernel_launch(void* const* d_in, const int* in_sizes, int n_in,
                              void* d_out, int out_size, void* d_ws, size_t ws_size,
                              hipStream_t stream) {
    const float* logits = (const float*)d_in[0];
    const float* temps  = (const float*)d_in[1];
    const int*   top_ks = (const int*)d_in[2];
    const float* top_ps = (const float*)d_in[3];
    const float* min_ps = (const float*)d_in[4];
    const float* u      = (const float*)d_in[5];
    __hip_bfloat16* out = (__hip_bfloat16*)d_out;

    char* wsb = (char*)d_ws;
    unsigned long long* cand = (unsigned long long*)wsb;   // 128*4*2048*8 = 8 MiB
    float* zpart = (float*)(wsb + (8u << 20));             // 512 f32
    int* cntc    = (int*)(zpart + BB * NCHH);              // 512 int

    k_hist<<<dim3(NCHH, BB), 1024, 0, stream>>>(logits, temps, cand, cntc, zpart, out);
    k_row<<<BB, 1024, 0, stream>>>(cand, cntc, temps, zpart,
                                   top_ks, top_ps, min_ps, u, out);
}